// Round 4
// baseline (383.214 us; speedup 1.0000x reference)
//
#include <hip/hip_runtime.h>
#include <hip/hip_bf16.h>
#include <stdint.h>

// ---------- helpers ----------
typedef __attribute__((ext_vector_type(8))) short bf16x8;
typedef __attribute__((ext_vector_type(4))) float f32x4;

__device__ __forceinline__ unsigned short f2bf(float f) {
    unsigned u = __float_as_uint(f);
    unsigned r = (u + 0x7fffu + ((u >> 16) & 1u)) >> 16;
    return (unsigned short)r;
}
__device__ __forceinline__ unsigned pack2(float lo, float hi) {
    return (unsigned)f2bf(lo) | ((unsigned)f2bf(hi) << 16);
}

__device__ __forceinline__ float wsum(float v) {
#pragma unroll
    for (int d = 32; d > 0; d >>= 1) v += __shfl_xor(v, d, 64);
    return v;
}
__device__ __forceinline__ float wmax(float v) {
#pragma unroll
    for (int d = 32; d > 0; d >>= 1) v = fmaxf(v, __shfl_xor(v, d, 64));
    return v;
}

// ---------- problem constants ----------
#define BT_ROWS 32768   // B*T
#define FDIM    512
#define NDIM    512
#define KSEQ    8.0f
#define LDW     40      // padded LDS row (elems): kills 8-way ds_read conflicts

// ---------- kernel 1: cast weights only (2 MB f32 -> 1 MB bf16) ----------
__global__ __launch_bounds__(256) void castw_kernel(
    const float* __restrict__ wb, const float* __restrict__ wv,
    unsigned short* __restrict__ wbb, unsigned short* __restrict__ wvb)
{
    const int nw4 = (NDIM * FDIM) >> 2;   // 65536 float4s per matrix
    int i = blockIdx.x * 256 + threadIdx.x;
    const float4* src; unsigned short* dst; int j;
    if (i < nw4)          { src = (const float4*)wb; dst = wbb; j = i; }
    else if (i < 2 * nw4) { src = (const float4*)wv; dst = wvb; j = i - nw4; }
    else return;
    float4 v = src[j];
    ushort4 o;
    o.x = f2bf(v.x); o.y = f2bf(v.y); o.z = f2bf(v.z); o.w = f2bf(v.w);
    *(ushort4*)(dst + 4 * (size_t)j) = o;
}

// ---------- kernel 2: fused dual GEMM, x read as f32 (cast in-register) ----------
// C_mat[m,n] = sum_k x[m,k] * W_mat[n,k], both mats per block (A staged once).
// 128x128 tile, BK=32, 256 threads = 4 waves (2x2); per wave 64x64 per mat.
// Reg-staged LDS with padded rows; next-K global loads prefetched under MFMA.
__global__ __launch_bounds__(256, 2) void gemm2_kernel(
    const float* __restrict__ X,
    const unsigned short* __restrict__ W0,
    const unsigned short* __restrict__ W1,
    unsigned short* __restrict__ C0,
    unsigned short* __restrict__ C1)
{
    __shared__ unsigned short lds[3 * 128 * LDW];   // A | B0 | B1, 30720 B
    unsigned short* sA  = lds;
    unsigned short* sB0 = lds + 128 * LDW;
    unsigned short* sB1 = lds + 256 * LDW;

    const int t = threadIdx.x, w = t >> 6, l = t & 63;

    // XCD-aware swizzle (nwg=1024, %8==0 -> simple form is bijective).
    // Decode so consecutive in-XCD ids share the A row-panel (bn varies fastest).
    int swz = ((blockIdx.x & 7) << 7) + (blockIdx.x >> 3);
    const int bm = swz >> 2, bn = swz & 3;

    // staging: 2 threads per row; each thread covers 16 k-elems
    const int sr = t >> 1;           // 0..127
    const int sk = (t & 1) << 4;     // 0 or 16
    const float*          gX  = X  + (size_t)(bm * 128 + sr) * FDIM + sk;
    const unsigned short* gB0 = W0 + (size_t)(bn * 128 + sr) * FDIM + sk;
    const unsigned short* gB1 = W1 + (size_t)(bn * 128 + sr) * FDIM + sk;
    const int wrow = sr * LDW + sk;  // LDS elem offset for this thread's writes

    // fragment read coords
    const int wm = w >> 1, wn = w & 1;
    const int lr = l & 15, lk = (l >> 4) * 8;

    f32x4 acc[2][4][4] = {};   // [mat][r][c], 128 f32 (static indexing only)

    float4 fa[4]; uint4 vb0[2], vb1[2];   // staging regs (A f32, B bf16)

    auto LOADK = [&](int kk) {
        const float* pa = gX + kk * 32;
        fa[0] = *(const float4*)(pa);
        fa[1] = *(const float4*)(pa + 4);
        fa[2] = *(const float4*)(pa + 8);
        fa[3] = *(const float4*)(pa + 12);
        const uint4* p0 = (const uint4*)(gB0 + kk * 32);
        vb0[0] = p0[0]; vb0[1] = p0[1];
        const uint4* p1 = (const uint4*)(gB1 + kk * 32);
        vb1[0] = p1[0]; vb1[1] = p1[1];
    };

    LOADK(0);
    for (int kk = 0; kk < 16; ++kk) {
        __syncthreads();   // previous iter's frag reads complete
        // cvt + LDS writes (16B aligned: wrow*2 = sr*80 + sk*2 in {0,32})
        {
            uint4 a0, a1;
            a0.x = pack2(fa[0].x, fa[0].y); a0.y = pack2(fa[0].z, fa[0].w);
            a0.z = pack2(fa[1].x, fa[1].y); a0.w = pack2(fa[1].z, fa[1].w);
            a1.x = pack2(fa[2].x, fa[2].y); a1.y = pack2(fa[2].z, fa[2].w);
            a1.z = pack2(fa[3].x, fa[3].y); a1.w = pack2(fa[3].z, fa[3].w);
            *(uint4*)&sA[wrow]      = a0;
            *(uint4*)&sA[wrow + 8]  = a1;
            *(uint4*)&sB0[wrow]     = vb0[0];
            *(uint4*)&sB0[wrow + 8] = vb0[1];
            *(uint4*)&sB1[wrow]     = vb1[0];
            *(uint4*)&sB1[wrow + 8] = vb1[1];
        }
        __syncthreads();   // tiles ready
        if (kk < 15) LOADK(kk + 1);   // prefetch overlaps frag reads + MFMA

        bf16x8 ar[4], br0[4], br1[4];
#pragma unroll
        for (int r = 0; r < 4; ++r)
            ar[r] = *(const bf16x8*)&sA[(wm * 64 + r * 16 + lr) * LDW + lk];
#pragma unroll
        for (int c = 0; c < 4; ++c) {
            br0[c] = *(const bf16x8*)&sB0[(wn * 64 + c * 16 + lr) * LDW + lk];
            br1[c] = *(const bf16x8*)&sB1[(wn * 64 + c * 16 + lr) * LDW + lk];
        }
#pragma unroll
        for (int r = 0; r < 4; ++r)
#pragma unroll
            for (int c = 0; c < 4; ++c) {
                acc[0][r][c] = __builtin_amdgcn_mfma_f32_16x16x32_bf16(ar[r], br0[c], acc[0][r][c], 0, 0, 0);
                acc[1][r][c] = __builtin_amdgcn_mfma_f32_16x16x32_bf16(ar[r], br1[c], acc[1][r][c], 0, 0, 0);
            }
    }

    // epilogue: C/D layout col = lane&15, row = (lane>>4)*4 + j  [m89]
    const int lg4 = (l >> 4) * 4;
#pragma unroll
    for (int r = 0; r < 4; ++r) {
        int row0 = bm * 128 + wm * 64 + r * 16 + lg4;
#pragma unroll
        for (int c = 0; c < 4; ++c) {
            int col = bn * 128 + wn * 64 + c * 16 + lr;
#pragma unroll
            for (int j = 0; j < 4; ++j) {
                C0[(size_t)(row0 + j) * NDIM + col] = f2bf(acc[0][r][c][j]);
                C1[(size_t)(row0 + j) * NDIM + col] = f2bf(acc[1][r][c][j]);
            }
        }
    }
}

// ---------- kernel 3: row-wise fused softmax / softmax / Newton / marginals / cumsum ----------
// one wave per row, 8 elems per lane; shuffle-only reductions and scan.
__global__ __launch_bounds__(256) void rowwise_kernel(
    const unsigned short* __restrict__ Lb,
    const unsigned short* __restrict__ Lv,
    float* __restrict__ out)
{
    const size_t S = (size_t)BT_ROWS * NDIM;
    const int row = blockIdx.x * 4 + (threadIdx.x >> 6);
    const int l = threadIdx.x & 63;
    const size_t base = (size_t)row * NDIM + l * 8;

    uint4 ub = *(const uint4*)(Lb + base);
    uint4 uv = *(const uint4*)(Lv + base);
    float xb[8], xv[8];
    {
        unsigned b[4] = {ub.x, ub.y, ub.z, ub.w};
        unsigned v[4] = {uv.x, uv.y, uv.z, uv.w};
#pragma unroll
        for (int i = 0; i < 4; ++i) {
            xb[2*i]   = __uint_as_float(b[i] << 16);
            xb[2*i+1] = __uint_as_float(b[i] & 0xffff0000u);
            xv[2*i]   = __uint_as_float(v[i] << 16);
            xv[2*i+1] = __uint_as_float(v[i] & 0xffff0000u);
        }
    }

    // softmax 1 -> probs
    float m1 = xb[0];
#pragma unroll
    for (int i = 1; i < 8; ++i) m1 = fmaxf(m1, xb[i]);
    m1 = wmax(m1);
    float p[8]; float s1 = 0.f;
#pragma unroll
    for (int i = 0; i < 8; ++i) { p[i] = __expf(xb[i] - m1); s1 += p[i]; }
    s1 = wsum(s1);
    float inv1 = 1.f / s1;
#pragma unroll
    for (int i = 0; i < 8; ++i) p[i] *= inv1;

    // softmax 2 -> values = softmax(probs + logits_values)
    float tv[8];
    float m2 = -1e30f;
#pragma unroll
    for (int i = 0; i < 8; ++i) { tv[i] = p[i] + xv[i]; m2 = fmaxf(m2, tv[i]); }
    m2 = wmax(m2);
    float s2 = 0.f;
#pragma unroll
    for (int i = 0; i < 8; ++i) { tv[i] = __expf(tv[i] - m2); s2 += tv[i]; }
    s2 = wsum(s2);
    float inv2 = 1.f / s2;

    // Newton for alpha
    float y[8];
#pragma unroll
    for (int i = 0; i < 8; ++i) y[i] = __logf(1.0f - p[i]);
    float alpha = KSEQ;
#pragma unroll
    for (int it = 0; it < 3; ++it) {
        float se = 0.f, sd = 0.f;
#pragma unroll
        for (int i = 0; i < 8; ++i) {
            float e = __expf(alpha * y[i]);
            se += e; sd += e * y[i];
        }
        se = wsum(se); sd = wsum(sd);
        float err = se + (KSEQ - (float)NDIM);
        alpha = alpha - err / sd;
    }

    // marginals
    float mg[8];
#pragma unroll
    for (int i = 0; i < 8; ++i) mg[i] = 1.0f - __expf(alpha * y[i]);

    // exclusive cumsum
    float loc = 0.f;
#pragma unroll
    for (int i = 0; i < 8; ++i) loc += p[i];
    float sc = loc;
#pragma unroll
    for (int d = 1; d < 64; d <<= 1) {
        float n = __shfl_up(sc, d, 64);
        if (l >= d) sc += n;
    }
    float run = sc - loc;
    float cum[8];
#pragma unroll
    for (int i = 0; i < 8; ++i) { cum[i] = run; run += p[i]; }

    float vals[8];
#pragma unroll
    for (int i = 0; i < 8; ++i) vals[i] = tv[i] * inv2;

    float4* omg = (float4*)(out + base);
    float4* ovl = (float4*)(out + S + base);
    float4* ocs = (float4*)(out + 2 * S + base);
    omg[0] = make_float4(mg[0], mg[1], mg[2], mg[3]);
    omg[1] = make_float4(mg[4], mg[5], mg[6], mg[7]);
    ovl[0] = make_float4(vals[0], vals[1], vals[2], vals[3]);
    ovl[1] = make_float4(vals[4], vals[5], vals[6], vals[7]);
    ocs[0] = make_float4(cum[0], cum[1], cum[2], cum[3]);
    ocs[1] = make_float4(cum[4], cum[5], cum[6], cum[7]);
}

// ---------- launch ----------
extern "C" void kernel_launch(void* const* d_in, const int* in_sizes, int n_in,
                              void* d_out, int out_size, void* d_ws, size_t ws_size,
                              hipStream_t stream) {
    const float* x  = (const float*)d_in[0];
    const float* wb = (const float*)d_in[1];
    const float* wv = (const float*)d_in[2];
    float* out = (float*)d_out;
    char* ws = (char*)d_ws;

    // ws layout: wbb 512KB | wvb 512KB | lgb 33.5MB | lgv 33.5MB  (~68MB, ws is ~805MB)
    unsigned short* wbb = (unsigned short*)(ws);
    unsigned short* wvb = (unsigned short*)(ws + 524288);
    unsigned short* lgb = (unsigned short*)(ws + 1048576);
    unsigned short* lgv = (unsigned short*)(ws + 1048576 + 33554432);

    // 1) cast weights to bf16 (tiny)
    castw_kernel<<<512, 256, 0, stream>>>(wb, wv, wbb, wvb);
    // 2) fused dual GEMM (x f32 -> in-reg bf16), both logits
    gemm2_kernel<<<1024, 256, 0, stream>>>(x, wbb, wvb, lgb, lgv);
    // 3) row-wise fusion -> 3 outputs
    rowwise_kernel<<<BT_ROWS / 4, 256, 0, stream>>>(lgb, lgv, out);
}